// Round 2
// baseline (636.359 us; speedup 1.0000x reference)
//
#include <hip/hip_runtime.h>
#include <hip/hip_bf16.h>

typedef __bf16 bf16x8 __attribute__((ext_vector_type(8)));
typedef __bf16 bf16x4 __attribute__((ext_vector_type(4)));
typedef float  floatx4 __attribute__((ext_vector_type(4)));

#define L_SEQ 4096

// ---------------- fp32 -> bf16 cast, 8 elems/thread ----------------
__global__ void cvt_bf16_kernel(const float* __restrict__ src,
                                __bf16* __restrict__ dst, int n8)
{
    int i = blockIdx.x * blockDim.x + threadIdx.x;
    if (i >= n8) return;
    const float4* s = (const float4*)src + (size_t)i * 2;
    float4 f0 = s[0], f1 = s[1];
    bf16x8 o;
    o[0] = (__bf16)f0.x; o[1] = (__bf16)f0.y; o[2] = (__bf16)f0.z; o[3] = (__bf16)f0.w;
    o[4] = (__bf16)f1.x; o[5] = (__bf16)f1.y; o[6] = (__bf16)f1.z; o[7] = (__bf16)f1.w;
    *((bf16x8*)dst + i) = o;
}

// ---------------- 3 weight transposes in one launch: dst[n][k] = (bf16)src[k][n] ----------------
__global__ void transpose_cvt3_kernel(const float* __restrict__ WQ,
                                      const float* __restrict__ WK,
                                      const float* __restrict__ WO,
                                      __bf16* __restrict__ Wqk,
                                      __bf16* __restrict__ Wo)
{
    const int z = blockIdx.z;
    const float* src = (z == 0) ? WQ : (z == 1) ? WK : WO;
    __bf16* dst = (z == 0) ? Wqk : (z == 1) ? (Wqk + (size_t)1024 * 1024) : Wo;

    __shared__ float tile[32][33];
    int tx = threadIdx.x & 31, ty = threadIdx.x >> 5;   // 32 x 8
    int n0 = blockIdx.x * 32, k0 = blockIdx.y * 32;
    #pragma unroll
    for (int i = 0; i < 32; i += 8)
        tile[ty + i][tx] = src[(size_t)(k0 + ty + i) * 1024 + n0 + tx];
    __syncthreads();
    #pragma unroll
    for (int i = 0; i < 32; i += 8)
        dst[(size_t)(n0 + ty + i) * 1024 + k0 + tx] = (__bf16)tile[tx][ty + i];
}

// ---------------- global-token projections ak/av (fp32, tiny) ----------------
// akv layout: [b][0][1024] = ak, [b][1][1024] = av. grid (8,2), 256 thr, 4 cols/thr
__global__ void akv_kernel(const float* __restrict__ ax,
                           const float* __restrict__ Wk, const float* __restrict__ bk,
                           const float* __restrict__ Wv, const float* __restrict__ bv,
                           float* __restrict__ akv)
{
    int b = blockIdx.x, kv = blockIdx.y;
    int n = threadIdx.x * 4;
    const float* W    = kv ? Wv : Wk;
    const float* bias = kv ? bv : bk;
    const float* axr  = ax + (size_t)b * 1024;
    float4 acc = *(const float4*)(bias + n);
    for (int k = 0; k < 1024; ++k) {
        float a = axr[k];
        float4 w = *(const float4*)(W + (size_t)k * 1024 + n);
        acc.x = fmaf(a, w.x, acc.x);
        acc.y = fmaf(a, w.y, acc.y);
        acc.z = fmaf(a, w.z, acc.z);
        acc.w = fmaf(a, w.w, acc.w);
    }
    *(float4*)(akv + ((size_t)b * 2 + kv) * 1024 + n) = acc;
}

// ---------------- bf16 MFMA GEMM: C[M][N] = A[M][K] * Bt[N][K]^T + bias ----------------
// m97 structure: 128x128 tile, BK=32, 4 waves, 4x4 16x16x32 MFMAs per wave,
// global_load_lds width=16 staging. XCD-aware 1-D grid: each XCD owns NPX
// n-tiles (its B-slice stays L2-resident) and walks all m-tiles; A-tiles hit
// L3 once. launch_bounds(256,4): 56 VGPR + 64 AGPR = 120 <= 128 budget.
template <int NPX, bool OUT_F32>
__global__ __launch_bounds__(256, 4) void gemm_bt_kernel(
    const __bf16* __restrict__ A, const __bf16* __restrict__ Bt,
    const float* __restrict__ b0, const float* __restrict__ b1, int nsplit,
    void* __restrict__ Cp, int M, int N, int K)
{
    __shared__ __bf16 As[128 * 32];   // 8 KB
    __shared__ __bf16 Bs[128 * 32];   // 8 KB
    const int bid  = blockIdx.x;
    const int xcd  = bid & 7, g = bid >> 3;
    const int nt   = xcd * NPX + (g % NPX);
    const int mt   = g / NPX;
    const int m0 = mt * 128, n0 = nt * 128;

    const int tid  = threadIdx.x;
    const int wave = tid >> 6, lane = tid & 63;
    const int quad = lane >> 4, l16 = lane & 15;
    const int wm = (wave >> 1) * 64, wn = (wave & 1) * 64;

    floatx4 acc[4][4] = {};

    const int srow  = lane >> 2;        // 0..15
    const int skcol = (lane & 3) * 8;   // 0,8,16,24

    for (int k0 = 0; k0 < K; k0 += 32) {
        if (k0) __syncthreads();
        #pragma unroll
        for (int c = 0; c < 2; ++c) {
            int chunk = wave * 2 + c;
            int row   = chunk * 16 + srow;
            __builtin_amdgcn_global_load_lds(
                (const __attribute__((address_space(1))) void*)(A + (size_t)(m0 + row) * K + k0 + skcol),
                (__attribute__((address_space(3))) void*)(As + chunk * 512),
                16, 0, 0);
            __builtin_amdgcn_global_load_lds(
                (const __attribute__((address_space(1))) void*)(Bt + (size_t)(n0 + row) * K + k0 + skcol),
                (__attribute__((address_space(3))) void*)(Bs + chunk * 512),
                16, 0, 0);
        }
        __syncthreads();

        bf16x8 af[4], bfr[4];
        #pragma unroll
        for (int mi = 0; mi < 4; ++mi)
            af[mi] = *(const bf16x8*)(As + (wm + mi * 16 + l16) * 32 + quad * 8);
        #pragma unroll
        for (int ni = 0; ni < 4; ++ni)
            bfr[ni] = *(const bf16x8*)(Bs + (wn + ni * 16 + l16) * 32 + quad * 8);
        #pragma unroll
        for (int mi = 0; mi < 4; ++mi)
            #pragma unroll
            for (int ni = 0; ni < 4; ++ni)
                acc[mi][ni] = __builtin_amdgcn_mfma_f32_16x16x32_bf16(
                    af[mi], bfr[ni], acc[mi][ni], 0, 0, 0);
    }

    // epilogue: C/D layout col = lane&15, row = quad*4 + r (m89/m91-verified)
    #pragma unroll
    for (int ni = 0; ni < 4; ++ni) {
        int gn = n0 + wn + ni * 16 + l16;
        float bv = (gn < nsplit) ? b0[gn] : b1[gn - nsplit];
        #pragma unroll
        for (int mi = 0; mi < 4; ++mi) {
            int gm = m0 + wm + mi * 16 + quad * 4;
            #pragma unroll
            for (int r = 0; r < 4; ++r) {
                float v = acc[mi][ni][r] + bv;
                if (OUT_F32)
                    ((float*)Cp)[(size_t)(gm + r) * N + gn] = v;
                else
                    ((__bf16*)Cp)[(size_t)(gm + r) * N + gn] = (__bf16)v;
            }
        }
    }
}

// ---------------- attention: 4 slots (ak | k[l-1],k[l],k[l+1]), V = (av | k...) ----------------
// qk row m (= b*L + l): [0:1024] = q (h*64+d), [1024:2048] = k
__global__ void attn_kernel(const __bf16* __restrict__ qk,
                            const float* __restrict__ akv,
                            __bf16* __restrict__ att)
{
    const int m = blockIdx.x;          // token index
    const int l = m & (L_SEQ - 1);
    const int b = m >> 12;
    const int t = threadIdx.x;         // 256: head = t>>4, 4 dims each
    const int c4 = t * 4;              // == head*64 + dim offset

    bf16x4 qv = *(const bf16x4*)(qk + (size_t)m * 2048 + c4);
    float q0 = qv[0], q1 = qv[1], q2 = qv[2], q3 = qv[3];

    float kx[3][4];
    #pragma unroll
    for (int j = 0; j < 3; ++j) {
        int ll = l + j - 1;
        if (ll >= 0 && ll < L_SEQ) {
            bf16x4 kv = *(const bf16x4*)(qk + (size_t)(m + j - 1) * 2048 + 1024 + c4);
            kx[j][0] = kv[0]; kx[j][1] = kv[1]; kx[j][2] = kv[2]; kx[j][3] = kv[3];
        } else {
            kx[j][0] = kx[j][1] = kx[j][2] = kx[j][3] = 0.f;  // zero-pad, still a softmax slot
        }
    }
    float4 av4 = *(const float4*)(akv + ((size_t)b * 2 + 0) * 1024 + c4);
    float4 vv4 = *(const float4*)(akv + ((size_t)b * 2 + 1) * 1024 + c4);

    float p0 = q0 * av4.x + q1 * av4.y + q2 * av4.z + q3 * av4.w;
    float p1 = q0 * kx[0][0] + q1 * kx[0][1] + q2 * kx[0][2] + q3 * kx[0][3];
    float p2 = q0 * kx[1][0] + q1 * kx[1][1] + q2 * kx[1][2] + q3 * kx[1][3];
    float p3 = q0 * kx[2][0] + q1 * kx[2][1] + q2 * kx[2][2] + q3 * kx[2][3];
    #pragma unroll
    for (int off = 1; off < 16; off <<= 1) {   // reduce within 16-lane head group
        p0 += __shfl_xor(p0, off, 64);
        p1 += __shfl_xor(p1, off, 64);
        p2 += __shfl_xor(p2, off, 64);
        p3 += __shfl_xor(p3, off, 64);
    }
    const float sc = 0.125f;   // 1/sqrt(64)
    float s0 = p0 * sc, s1 = p1 * sc, s2 = p2 * sc, s3 = p3 * sc;
    float mx = fmaxf(fmaxf(s0, s1), fmaxf(s2, s3));
    float e0 = __expf(s0 - mx), e1 = __expf(s1 - mx), e2 = __expf(s2 - mx), e3 = __expf(s3 - mx);
    float inv = 1.f / (e0 + e1 + e2 + e3);

    bf16x4 o;
    o[0] = (__bf16)((e0 * vv4.x + e1 * kx[0][0] + e2 * kx[1][0] + e3 * kx[2][0]) * inv);
    o[1] = (__bf16)((e0 * vv4.y + e1 * kx[0][1] + e2 * kx[1][1] + e3 * kx[2][1]) * inv);
    o[2] = (__bf16)((e0 * vv4.z + e1 * kx[0][2] + e2 * kx[1][2] + e3 * kx[2][2]) * inv);
    o[3] = (__bf16)((e0 * vv4.w + e1 * kx[0][3] + e2 * kx[1][3] + e3 * kx[2][3]) * inv);
    *(bf16x4*)(att + (size_t)m * 1024 + c4) = o;
}

extern "C" void kernel_launch(void* const* d_in, const int* in_sizes, int n_in,
                              void* d_out, int out_size, void* d_ws, size_t ws_size,
                              hipStream_t stream)
{
    const float* x    = (const float*)d_in[0];
    const float* ax   = (const float*)d_in[1];
    const float* WQ_w = (const float*)d_in[2];
    const float* WQ_b = (const float*)d_in[3];
    const float* WK_w = (const float*)d_in[4];
    const float* WK_b = (const float*)d_in[5];
    const float* WV_w = (const float*)d_in[6];
    const float* WV_b = (const float*)d_in[7];
    const float* WO_w = (const float*)d_in[8];
    const float* WO_b = (const float*)d_in[9];
    float* out = (float*)d_out;

    const int M = 8 * 4096;          // 32768 tokens

    // workspace layout
    char* ws = (char*)d_ws;
    __bf16* xb   = (__bf16*)(ws);                       //  67,108,864 B
    __bf16* Wqk  = (__bf16*)(ws + 67108864);            //   4,194,304 B  (2048 x 1024, N-major)
    __bf16* Wo   = (__bf16*)(ws + 71303168);            //   2,097,152 B  (1024 x 1024, N-major)
    __bf16* qk   = (__bf16*)(ws + 73400320);            // 134,217,728 B  (M x 2048)
    __bf16* att  = (__bf16*)(ws + 207618048);           //  67,108,864 B  (M x 1024)
    float*  akv  = (float*)(ws + 274726912);            //      65,536 B

    // 1) x -> bf16
    {
        int n8 = (M * 1024) / 8;   // 4,194,304
        cvt_bf16_kernel<<<n8 / 256, 256, 0, stream>>>(x, xb, n8);
    }
    // 2) weight transpose+cast (one launch): Wqk rows 0..1023 = WQ^T, 1024..2047 = WK^T; Wo = WO^T
    transpose_cvt3_kernel<<<dim3(32, 32, 3), 256, 0, stream>>>(WQ_w, WK_w, WO_w, Wqk, Wo);
    // 3) global token projections (fp32)
    akv_kernel<<<dim3(8, 2), 256, 0, stream>>>(ax, WK_w, WK_b, WV_w, WV_b, akv);
    // 4) fused Q|K projection GEMM: (M x 2048) = xb (M x 1024) @ [WQ|WK]; NPX=2 (16 n-tiles / 8 XCDs)
    gemm_bt_kernel<2, false><<<(M / 128) * 16, 256, 0, stream>>>(
        xb, Wqk, WQ_b, WK_b, 1024, (void*)qk, M, 2048, 1024);
    // 5) attention -> att (bf16)
    attn_kernel<<<M, 256, 0, stream>>>(qk, akv, att);
    // 6) output projection: out (M x 1024 fp32) = att @ WO + WO_b; NPX=1 (8 n-tiles / 8 XCDs)
    gemm_bt_kernel<1, true><<<(M / 128) * 8, 256, 0, stream>>>(
        att, Wo, WO_b, WO_b, 1024, (void*)out, M, 1024, 1024);
}

// Round 3
// 577.941 us; speedup vs baseline: 1.1011x; 1.1011x over previous
//
#include <hip/hip_runtime.h>
#include <hip/hip_bf16.h>

typedef __bf16 bf16x8 __attribute__((ext_vector_type(8)));
typedef __bf16 bf16x4 __attribute__((ext_vector_type(4)));
typedef float  floatx4 __attribute__((ext_vector_type(4)));

#define L_SEQ 4096

// ---------------- fp32 -> bf16 cast, 8 elems/thread ----------------
__global__ void cvt_bf16_kernel(const float* __restrict__ src,
                                __bf16* __restrict__ dst, int n8)
{
    int i = blockIdx.x * blockDim.x + threadIdx.x;
    if (i >= n8) return;
    const float4* s = (const float4*)src + (size_t)i * 2;
    float4 f0 = s[0], f1 = s[1];
    bf16x8 o;
    o[0] = (__bf16)f0.x; o[1] = (__bf16)f0.y; o[2] = (__bf16)f0.z; o[3] = (__bf16)f0.w;
    o[4] = (__bf16)f1.x; o[5] = (__bf16)f1.y; o[6] = (__bf16)f1.z; o[7] = (__bf16)f1.w;
    *((bf16x8*)dst + i) = o;
}

// ---------------- 3 weight transposes in one launch: dst[n][k] = (bf16)src[k][n] ----------------
__global__ void transpose_cvt3_kernel(const float* __restrict__ WQ,
                                      const float* __restrict__ WK,
                                      const float* __restrict__ WO,
                                      __bf16* __restrict__ Wqk,
                                      __bf16* __restrict__ Wo)
{
    const int z = blockIdx.z;
    const float* src = (z == 0) ? WQ : (z == 1) ? WK : WO;
    __bf16* dst = (z == 0) ? Wqk : (z == 1) ? (Wqk + (size_t)1024 * 1024) : Wo;

    __shared__ float tile[32][33];
    int tx = threadIdx.x & 31, ty = threadIdx.x >> 5;   // 32 x 8
    int n0 = blockIdx.x * 32, k0 = blockIdx.y * 32;
    #pragma unroll
    for (int i = 0; i < 32; i += 8)
        tile[ty + i][tx] = src[(size_t)(k0 + ty + i) * 1024 + n0 + tx];
    __syncthreads();
    #pragma unroll
    for (int i = 0; i < 32; i += 8)
        dst[(size_t)(n0 + ty + i) * 1024 + k0 + tx] = (__bf16)tile[tx][ty + i];
}

// ---------------- global-token projections, k-split x8 ----------------
// part[b][kv][z][1024]; grid (8,2,8), 256 thr, 4 cols/thr
__global__ void akv_part_kernel(const float* __restrict__ ax,
                                const float* __restrict__ Wk,
                                const float* __restrict__ Wv,
                                float* __restrict__ part)
{
    int b = blockIdx.x, kv = blockIdx.y, z = blockIdx.z;
    int n = threadIdx.x * 4;
    const float* W   = kv ? Wv : Wk;
    const float* axr = ax + (size_t)b * 1024 + z * 128;
    float4 acc = {0.f, 0.f, 0.f, 0.f};
    for (int k = 0; k < 128; ++k) {
        float a = axr[k];
        float4 w = *(const float4*)(W + (size_t)(z * 128 + k) * 1024 + n);
        acc.x = fmaf(a, w.x, acc.x);
        acc.y = fmaf(a, w.y, acc.y);
        acc.z = fmaf(a, w.z, acc.z);
        acc.w = fmaf(a, w.w, acc.w);
    }
    *(float4*)(part + (((size_t)(b * 2 + kv)) * 8 + z) * 1024 + n) = acc;
}

// akv[b][kv][1024] = bias + sum_z part; grid (8,2), 256 thr
__global__ void akv_reduce_kernel(const float* __restrict__ part,
                                  const float* __restrict__ bk,
                                  const float* __restrict__ bv,
                                  float* __restrict__ akv)
{
    int b = blockIdx.x, kv = blockIdx.y;
    int n = threadIdx.x * 4;
    float4 acc = *(const float4*)((kv ? bv : bk) + n);
    #pragma unroll
    for (int z = 0; z < 8; ++z) {
        float4 p = *(const float4*)(part + (((size_t)(b * 2 + kv)) * 8 + z) * 1024 + n);
        acc.x += p.x; acc.y += p.y; acc.z += p.z; acc.w += p.w;
    }
    *(float4*)(akv + ((size_t)b * 2 + kv) * 1024 + n) = acc;
}

// ---------------- bf16 MFMA GEMM: C[M][N] = A[M][K] * Bt[N][K]^T + bias ----------------
// m97 structure: 128x128 tile, BK=32, 4 waves, 4x4 16x16x32 MFMAs per wave,
// global_load_lds width=16 staging. XCD-aware 1-D grid; launch_bounds(256,4).
template <int NPX, bool OUT_F32>
__global__ __launch_bounds__(256, 4) void gemm_bt_kernel(
    const __bf16* __restrict__ A, const __bf16* __restrict__ Bt,
    const float* __restrict__ b0, const float* __restrict__ b1, int nsplit,
    void* __restrict__ Cp, int M, int N, int K)
{
    __shared__ __bf16 As[128 * 32];   // 8 KB
    __shared__ __bf16 Bs[128 * 32];   // 8 KB
    const int bid  = blockIdx.x;
    const int xcd  = bid & 7, g = bid >> 3;
    const int nt   = xcd * NPX + (g % NPX);
    const int mt   = g / NPX;
    const int m0 = mt * 128, n0 = nt * 128;

    const int tid  = threadIdx.x;
    const int wave = tid >> 6, lane = tid & 63;
    const int quad = lane >> 4, l16 = lane & 15;
    const int wm = (wave >> 1) * 64, wn = (wave & 1) * 64;

    floatx4 acc[4][4] = {};

    const int srow  = lane >> 2;        // 0..15
    const int skcol = (lane & 3) * 8;   // 0,8,16,24

    for (int k0 = 0; k0 < K; k0 += 32) {
        if (k0) __syncthreads();
        #pragma unroll
        for (int c = 0; c < 2; ++c) {
            int chunk = wave * 2 + c;
            int row   = chunk * 16 + srow;
            __builtin_amdgcn_global_load_lds(
                (const __attribute__((address_space(1))) void*)(A + (size_t)(m0 + row) * K + k0 + skcol),
                (__attribute__((address_space(3))) void*)(As + chunk * 512),
                16, 0, 0);
            __builtin_amdgcn_global_load_lds(
                (const __attribute__((address_space(1))) void*)(Bt + (size_t)(n0 + row) * K + k0 + skcol),
                (__attribute__((address_space(3))) void*)(Bs + chunk * 512),
                16, 0, 0);
        }
        __syncthreads();

        bf16x8 af[4], bfr[4];
        #pragma unroll
        for (int mi = 0; mi < 4; ++mi)
            af[mi] = *(const bf16x8*)(As + (wm + mi * 16 + l16) * 32 + quad * 8);
        #pragma unroll
        for (int ni = 0; ni < 4; ++ni)
            bfr[ni] = *(const bf16x8*)(Bs + (wn + ni * 16 + l16) * 32 + quad * 8);
        #pragma unroll
        for (int mi = 0; mi < 4; ++mi)
            #pragma unroll
            for (int ni = 0; ni < 4; ++ni)
                acc[mi][ni] = __builtin_amdgcn_mfma_f32_16x16x32_bf16(
                    af[mi], bfr[ni], acc[mi][ni], 0, 0, 0);
    }

    // epilogue: C/D layout col = lane&15, row = quad*4 + r (m89/m91-verified)
    #pragma unroll
    for (int ni = 0; ni < 4; ++ni) {
        int gn = n0 + wn + ni * 16 + l16;
        float bv = (gn < nsplit) ? b0[gn] : b1[gn - nsplit];
        #pragma unroll
        for (int mi = 0; mi < 4; ++mi) {
            int gm = m0 + wm + mi * 16 + quad * 4;
            #pragma unroll
            for (int r = 0; r < 4; ++r) {
                float v = acc[mi][ni][r] + bv;
                if (OUT_F32)
                    ((float*)Cp)[(size_t)(gm + r) * N + gn] = v;
                else
                    ((__bf16*)Cp)[(size_t)(gm + r) * N + gn] = (__bf16)v;
            }
        }
    }
}

// ---------------- attention: 8 tokens per block ----------------
// qk row m (= b*L + l): [0:1024] = q (h*64+d), [1024:2048] = k
// 4 slots: (ak | k[l-1], k[l], k[l+1]); V = (av | same k's)
__global__ void attn_kernel(const __bf16* __restrict__ qk,
                            const float* __restrict__ akv,
                            __bf16* __restrict__ att)
{
    const int t  = threadIdx.x;        // head = t>>4, 4 dims each
    const int c4 = t * 4;
    const int m0 = blockIdx.x * 8;     // 8 consecutive tokens, same batch (8 | 4096)
    const int l0 = m0 & (L_SEQ - 1);
    const int b  = m0 >> 12;

    // k-window rows m0-1 .. m0+8 (10 rows), zero outside the sequence
    float kr[10][4];
    #pragma unroll
    for (int j = 0; j < 10; ++j) {
        int ll = l0 - 1 + j;
        if (ll >= 0 && ll < L_SEQ) {
            bf16x4 kv = *(const bf16x4*)(qk + (size_t)(m0 - 1 + j) * 2048 + 1024 + c4);
            kr[j][0] = kv[0]; kr[j][1] = kv[1]; kr[j][2] = kv[2]; kr[j][3] = kv[3];
        } else {
            kr[j][0] = kr[j][1] = kr[j][2] = kr[j][3] = 0.f;
        }
    }
    float4 ak4 = *(const float4*)(akv + ((size_t)b * 2 + 0) * 1024 + c4);
    float4 av4 = *(const float4*)(akv + ((size_t)b * 2 + 1) * 1024 + c4);

    #pragma unroll
    for (int i = 0; i < 8; ++i) {
        const int m = m0 + i;
        bf16x4 qv = *(const bf16x4*)(qk + (size_t)m * 2048 + c4);
        float q0 = qv[0], q1 = qv[1], q2 = qv[2], q3 = qv[3];

        float p0 = q0 * ak4.x + q1 * ak4.y + q2 * ak4.z + q3 * ak4.w;
        float p1 = q0 * kr[i][0]     + q1 * kr[i][1]     + q2 * kr[i][2]     + q3 * kr[i][3];
        float p2 = q0 * kr[i + 1][0] + q1 * kr[i + 1][1] + q2 * kr[i + 1][2] + q3 * kr[i + 1][3];
        float p3 = q0 * kr[i + 2][0] + q1 * kr[i + 2][1] + q2 * kr[i + 2][2] + q3 * kr[i + 2][3];
        #pragma unroll
        for (int off = 1; off < 16; off <<= 1) {   // reduce within 16-lane head group
            p0 += __shfl_xor(p0, off, 64);
            p1 += __shfl_xor(p1, off, 64);
            p2 += __shfl_xor(p2, off, 64);
            p3 += __shfl_xor(p3, off, 64);
        }
        const float sc = 0.125f;   // 1/sqrt(64)
        float s0 = p0 * sc, s1 = p1 * sc, s2 = p2 * sc, s3 = p3 * sc;
        float mx = fmaxf(fmaxf(s0, s1), fmaxf(s2, s3));
        float e0 = __expf(s0 - mx), e1 = __expf(s1 - mx), e2 = __expf(s2 - mx), e3 = __expf(s3 - mx);
        float inv = 1.f / (e0 + e1 + e2 + e3);

        bf16x4 o;
        o[0] = (__bf16)((e0 * av4.x + e1 * kr[i][0] + e2 * kr[i + 1][0] + e3 * kr[i + 2][0]) * inv);
        o[1] = (__bf16)((e0 * av4.y + e1 * kr[i][1] + e2 * kr[i + 1][1] + e3 * kr[i + 2][1]) * inv);
        o[2] = (__bf16)((e0 * av4.z + e1 * kr[i][2] + e2 * kr[i + 1][2] + e3 * kr[i + 2][2]) * inv);
        o[3] = (__bf16)((e0 * av4.w + e1 * kr[i][3] + e2 * kr[i + 1][3] + e3 * kr[i + 2][3]) * inv);
        *(bf16x4*)(att + (size_t)m * 1024 + c4) = o;
    }
}

extern "C" void kernel_launch(void* const* d_in, const int* in_sizes, int n_in,
                              void* d_out, int out_size, void* d_ws, size_t ws_size,
                              hipStream_t stream)
{
    const float* x    = (const float*)d_in[0];
    const float* ax   = (const float*)d_in[1];
    const float* WQ_w = (const float*)d_in[2];
    const float* WQ_b = (const float*)d_in[3];
    const float* WK_w = (const float*)d_in[4];
    const float* WK_b = (const float*)d_in[5];
    const float* WV_w = (const float*)d_in[6];
    const float* WV_b = (const float*)d_in[7];
    const float* WO_w = (const float*)d_in[8];
    const float* WO_b = (const float*)d_in[9];
    float* out = (float*)d_out;

    const int M = 8 * 4096;          // 32768 tokens

    // workspace layout
    char* ws = (char*)d_ws;
    __bf16* xb   = (__bf16*)(ws);                       //  67,108,864 B
    __bf16* Wqk  = (__bf16*)(ws + 67108864);            //   4,194,304 B  (2048 x 1024, N-major)
    __bf16* Wo   = (__bf16*)(ws + 71303168);            //   2,097,152 B  (1024 x 1024, N-major)
    __bf16* qk   = (__bf16*)(ws + 73400320);            // 134,217,728 B  (M x 2048)
    __bf16* att  = (__bf16*)(ws + 207618048);           //  67,108,864 B  (M x 1024)
    float*  akv  = (float*)(ws + 274726912);            //      65,536 B
    float*  akvp = (float*)(ws + 274792448);            //     524,288 B  (partials)

    // 1) x -> bf16
    {
        int n8 = (M * 1024) / 8;   // 4,194,304
        cvt_bf16_kernel<<<n8 / 256, 256, 0, stream>>>(x, xb, n8);
    }
    // 2) weight transpose+cast (one launch)
    transpose_cvt3_kernel<<<dim3(32, 32, 3), 256, 0, stream>>>(WQ_w, WK_w, WO_w, Wqk, Wo);
    // 3) global token projections (fp32), k-split + reduce
    akv_part_kernel<<<dim3(8, 2, 8), 256, 0, stream>>>(ax, WK_w, WV_w, akvp);
    akv_reduce_kernel<<<dim3(8, 2), 256, 0, stream>>>(akvp, WK_b, WV_b, akv);
    // 4) fused Q|K projection GEMM: (M x 2048) = xb @ [WQ|WK]; NPX=2
    gemm_bt_kernel<2, false><<<(M / 128) * 16, 256, 0, stream>>>(
        xb, Wqk, WQ_b, WK_b, 1024, (void*)qk, M, 2048, 1024);
    // 5) attention -> att (bf16), 8 tokens/block
    attn_kernel<<<M / 8, 256, 0, stream>>>(qk, akv, att);
    // 6) output projection: out (M x 1024 fp32) = att @ WO + WO_b; NPX=1
    gemm_bt_kernel<1, true><<<(M / 128) * 8, 256, 0, stream>>>(
        att, Wo, WO_b, WO_b, 1024, (void*)out, M, 1024, 1024);
}